// Round 2
// baseline (4267.608 us; speedup 1.0000x reference)
//
#include <hip/hip_runtime.h>
#include <hip/hip_cooperative_groups.h>
#include <cstddef>
#include <cstdint>

namespace cg = cooperative_groups;

typedef _Float16 h4 __attribute__((ext_vector_type(4)));
typedef _Float16 h8 __attribute__((ext_vector_type(8)));
typedef float    f4 __attribute__((ext_vector_type(4)));

#define NN      50000
#define IND     512
#define HIDN    256
#define E2P     400000
#define EDD     800000
#define NBLK    196   // ceil(NN/256)
#define NBP     782   // cooperative grid: 782*256 = 200192 threads, 2 pairs/thread
#define TPT     200192

// ---- workspace layout (bytes) ----
// logf (f16 [EDD][8] = 12.8MB) aliases hf (dead after k_edge)
#define OFF_HF16    ((size_t)0)            // 25,600,000  f16 h [NN][256]
#define OFF_LOGF    ((size_t)0)            // 12,800,000  f16 [EDD][8] (CSR order)
#define OFF_Z       ((size_t)25600000)     //  3,200,000  f32 [NN][16]: [0:8]=log_phi, [8:16]=S
#define OFF_DEG     ((size_t)28800000)     //    200,000  int
#define OFF_LOGDEG  ((size_t)29000000)     //    200,000  f32
#define OFF_DEGC    ((size_t)29200000)     //    200,000  f32
#define OFF_BASE    ((size_t)29400000)     //    200,000  int (CSR exclusive scan)
#define OFF_CNT     ((size_t)29600000)     //    200,000  int (scan scratch / fill counters)
#define OFF_BLK     ((size_t)29800000)     //      4,096  int (scan block sums)
#define OFF_WT      ((size_t)29804096)     //    262,144  f16 enc_w1^T
#define OFF_BT      ((size_t)30066240)     //     69,632  f16 edge_w1 perm^T (h8-gather K-order)
#define OFF_RS      ((size_t)30135872)     //        512  f32 Rs[64] + alpha at [64]
#define OFF_WSYM    ((size_t)30136384)     //  1,600,000  f32 [E2P]
#define OFF_ENORM   ((size_t)31736384)     //  1,600,000  f32 [E2P] (fallback path only)
#define OFF_POS     ((size_t)33336384)     //  3,200,000  int [EDD] CSR slot of each directed edge
#define OFF_MA      ((size_t)36536384)     // 12,800,000  f16 [EDD][8] (fallback path only)
#define OFF_MB      ((size_t)49336384)     // 12,800,000  (fallback path only)
#define WS_NEED     ((size_t)62136384)

// ---------------- degree count ----------------
__global__ void k_deg(const int* __restrict__ ei, int* __restrict__ deg) {
    int e = blockIdx.x * 256 + threadIdx.x;   // grid exact: EDD
    atomicAdd(&deg[ei[e]], 1);
}

__global__ void k_node(const int* __restrict__ deg, float* __restrict__ logdeg,
                       float* __restrict__ degc) {
    int n = blockIdx.x * 256 + threadIdx.x;
    if (n < NN) {
        float d = (float)deg[n];
        logdeg[n] = logf(d + 1.0f);
        degc[n]   = fmaxf(d, 1.0f);
    }
}

// ---------------- CSR prefix-sum (3 tiny kernels) ----------------
__global__ void k_scan1(const int* __restrict__ deg, int* __restrict__ incl,
                        int* __restrict__ blk) {
    __shared__ int sm[256];
    int i = blockIdx.x * 256 + threadIdx.x;
    int v = (i < NN) ? deg[i] : 0;
    sm[threadIdx.x] = v;
    __syncthreads();
    for (int off = 1; off < 256; off <<= 1) {
        int t = (threadIdx.x >= off) ? sm[threadIdx.x - off] : 0;
        __syncthreads();
        sm[threadIdx.x] += t;
        __syncthreads();
    }
    if (i < NN) incl[i] = sm[threadIdx.x];
    if (threadIdx.x == 255) blk[blockIdx.x] = sm[255];
}

__global__ void k_scan2(int* __restrict__ blk) {
    __shared__ int sm[256];
    int v = (threadIdx.x < NBLK) ? blk[threadIdx.x] : 0;
    sm[threadIdx.x] = v;
    __syncthreads();
    for (int off = 1; off < 256; off <<= 1) {
        int t = (threadIdx.x >= off) ? sm[threadIdx.x - off] : 0;
        __syncthreads();
        sm[threadIdx.x] += t;
        __syncthreads();
    }
    if (threadIdx.x < NBLK) blk[threadIdx.x] = sm[threadIdx.x];
}

__global__ void k_scan3(const int* __restrict__ incl, const int* __restrict__ deg,
                        const int* __restrict__ blk, int* __restrict__ base) {
    int i = blockIdx.x * 256 + threadIdx.x;
    if (i < NN) {
        int off = (blockIdx.x > 0) ? blk[blockIdx.x - 1] : 0;
        base[i] = off + incl[i] - deg[i];
    }
}

// pos[e] = CSR slot of directed edge e within its dst node's segment
__global__ void k_pos(const int* __restrict__ ei, const int* __restrict__ base,
                      int* __restrict__ cnt, int* __restrict__ pos) {
    int e = blockIdx.x * 256 + threadIdx.x;   // grid exact: EDD
    int dstn = ei[EDD + e];
    pos[e] = base[dstn] + atomicAdd(&cnt[dstn], 1);
}

// ---------------- weight prep ----------------
// Bt K-order for h8 gathers: MFMA step tm (0..15), lane q, element e=2j+typ
//   k' = tm*32 + q*8 + 2j + typ  <->  column c = (tm>>1)*32 + q*8 + (tm&1)*4 + j
//   typ 0 = product feature (row c), typ 1 = absdiff (row 256+c). k'=512,513: struct.
__global__ void k_prep(const float* __restrict__ enc_w1, const float* __restrict__ edge_w1,
                       const float* __restrict__ R_raw, const float* __restrict__ Rsl,
                       const float* __restrict__ mlog,
                       _Float16* __restrict__ Wt, _Float16* __restrict__ Bt,
                       float* __restrict__ Rs) {
    int gid = blockIdx.x * 256 + threadIdx.x;
    if (gid < 256 * 512) {                       // Wt[n][k] = enc_w1[k][n]
        int n = gid >> 9, k = gid & 511;
        Wt[n * 512 + k] = (_Float16)enc_w1[k * 256 + n];
        return;
    }
    int g2 = gid - 256 * 512;
    if (g2 < 64 * 544) {                         // Bt[n][k'] with h8-gather K perm
        int n = g2 / 544, k = g2 - n * 544;
        float v = 0.0f;
        if (k < 512) {
            int tm = k >> 5, r = k & 31;
            int qq = r >> 3, jj = (r >> 1) & 3, typ = k & 1;
            int c = (tm >> 1) * 32 + qq * 8 + (tm & 1) * 4 + jj;
            v = edge_w1[(typ ? 256 + c : c) * 64 + n];
        } else if (k < 514) {
            v = edge_w1[k * 64 + n];
        }
        Bt[n * 544 + k] = (_Float16)v;
        return;
    }
    int g3 = g2 - 64 * 544;
    if (g3 < 64) {
        int c = g3 >> 3, d = g3 & 7;
        float rv = 0.5f * (R_raw[c * 8 + d] + R_raw[d * 8 + c]);
        float s  = log1pf(expf(Rsl[0])) + 1e-6f;
        Rs[g3] = s * tanhf(rv);
        return;
    }
    if (g3 == 64) {
        Rs[64] = 1.5f / (1.0f + expf(-mlog[0]));
    }
}

// ---------------- encoder layer 1: h = relu(x @ enc_w1 + b1), f16 MFMA ----------------
__global__ __launch_bounds__(256) void k_enc(const float* __restrict__ x,
                                             const _Float16* __restrict__ Wt,
                                             const float* __restrict__ b1,
                                             _Float16* __restrict__ hf) {
    __shared__ _Float16 XL[64 * 40];
    __shared__ _Float16 WL[256 * 40];
    const int tid = threadIdx.x;
    const int wid = tid >> 6;
    const int lane = tid & 63;
    const int l15 = lane & 15;
    const int q = lane >> 4;
    const int m0 = blockIdx.x * 64;

    f4 acc[16];
#pragma unroll
    for (int i = 0; i < 16; i++) acc[i] = (f4){0.f, 0.f, 0.f, 0.f};

    const int xr = tid >> 2;
    const int xs = tid & 3;
    const int gr = m0 + xr;

    for (int kt = 0; kt < 16; kt++) {
        __syncthreads();
        f4 xv0 = (f4){0, 0, 0, 0}, xv1 = (f4){0, 0, 0, 0};
        if (gr < NN) {
            const f4* xp = (const f4*)(x + (size_t)gr * IND + kt * 32 + xs * 8);
            xv0 = xp[0]; xv1 = xp[1];
        }
        h8 xh;
#pragma unroll
        for (int u = 0; u < 4; u++) { xh[u] = (_Float16)xv0[u]; xh[4 + u] = (_Float16)xv1[u]; }
        *(h8*)&XL[xr * 40 + xs * 8] = xh;
#pragma unroll
        for (int rep = 0; rep < 4; rep++) {
            int cid = rep * 256 + tid;
            int n = cid >> 2;
            int off = (cid & 3) * 8;
            h8 wv = *(const h8*)(Wt + (size_t)n * IND + kt * 32 + off);
            *(h8*)&WL[n * 40 + off] = wv;
        }
        __syncthreads();
        h8 a = *(const h8*)&XL[(wid * 16 + l15) * 40 + q * 8];
#pragma unroll
        for (int nt = 0; nt < 16; nt++) {
            h8 b = *(const h8*)&WL[(nt * 16 + l15) * 40 + q * 8];
            acc[nt] = __builtin_amdgcn_mfma_f32_16x16x32_f16(a, b, acc[nt], 0, 0, 0);
        }
    }
#pragma unroll
    for (int nt = 0; nt < 16; nt++) {
        int col = nt * 16 + l15;
        float bv = b1[col];
#pragma unroll
        for (int reg = 0; reg < 4; reg++) {
            int row = m0 + wid * 16 + q * 4 + reg;
            if (row < NN) {
                float v = acc[nt][reg] + bv;
                hf[(size_t)row * HIDN + col] = (_Float16)fmaxf(v, 0.f);
            }
        }
    }
}

// ---------------- encoder layer 2 + log_softmax -> Z[n][0:8] ----------------
__global__ void k_logits(const _Float16* __restrict__ hf, const float* __restrict__ w2,
                         const float* __restrict__ b2, float* __restrict__ Z) {
    __shared__ float w2L[2048];
    for (int i = threadIdx.x; i < 2048; i += 256) w2L[i] = w2[i];
    __syncthreads();
    int n = blockIdx.x * 256 + threadIdx.x;
    if (n >= NN) return;
    float sum[8];
#pragma unroll
    for (int c = 0; c < 8; c++) sum[c] = b2[c];
    for (int kb = 0; kb < 32; kb++) {
        h8 hv = *(const h8*)(hf + (size_t)n * HIDN + kb * 8);
#pragma unroll
        for (int u = 0; u < 8; u++) {
            float hx = (float)hv[u];
            const float* wr = &w2L[(kb * 8 + u) * 8];
#pragma unroll
            for (int c = 0; c < 8; c++) sum[c] += hx * wr[c];
        }
    }
    float mx = sum[0];
#pragma unroll
    for (int c = 1; c < 8; c++) mx = fmaxf(mx, sum[c]);
    float se = 0.f;
#pragma unroll
    for (int c = 0; c < 8; c++) se += __expf(sum[c] - mx);
    float lse = __logf(se);
#pragma unroll
    for (int c = 0; c < 8; c++) Z[(size_t)n * 16 + c] = sum[c] - mx - lse;
}

// ---------------- edge MLP: mt=2, 2x blocks for occupancy; h8 gathers + prefetch ------
__global__ __launch_bounds__(256) void k_edge(const int* __restrict__ ei,
        const _Float16* __restrict__ hf, const float* __restrict__ logdeg,
        const _Float16* __restrict__ BtG, const float* __restrict__ eb1,
        const float* __restrict__ ew2, const float* __restrict__ eb2,
        float* __restrict__ wsym) {
    __shared__ _Float16 BtL[64 * 136];
    const int tid = threadIdx.x;
    const int wid = tid >> 6;
    const int lane = tid & 63;
    const int l15 = lane & 15;
    const int q = lane >> 4;
    const int eb = blockIdx.x * 128;             // grid exact: E2P/128 = 3125

    int sidx[2], didx[2];
    float la[2], lb[2];
#pragma unroll
    for (int mt = 0; mt < 2; mt++) {
        int e = eb + wid * 32 + mt * 16 + l15;   // always < E2P
        sidx[mt] = ei[e];
        didx[mt] = ei[EDD + e];
        la[mt] = logdeg[sidx[mt]];
        lb[mt] = logdeg[didx[mt]];
    }

    f4 acc[2][4];
#pragma unroll
    for (int a = 0; a < 2; a++)
#pragma unroll
        for (int b = 0; b < 4; b++) acc[a][b] = (f4){0.f, 0.f, 0.f, 0.f};

    const _Float16* hq = hf + q * 8;            // lane's 16B column slice
    h8 curS[2], curD[2];
#pragma unroll
    for (int mt = 0; mt < 2; mt++) {            // kk=0 fragments (cols q*8..q*8+7)
        curS[mt] = *(const h8*)(hq + (size_t)sidx[mt] * HIDN);
        curD[mt] = *(const h8*)(hq + (size_t)didx[mt] * HIDN);
    }

    for (int ph = 0; ph < 4; ph++) {
        __syncthreads();
        {   // stage 64 rows x 128 cols of Bt
            const int r = tid & 63;
            const int cb = tid >> 6;
            const int kbase = ph * 128;
#pragma unroll
            for (int i = 0; i < 4; i++) {
                int ck = cb + i * 4;
                *(h8*)&BtL[r * 136 + ck * 8] =
                    *(const h8*)(BtG + (size_t)r * 544 + kbase + ck * 8);
            }
        }
        __syncthreads();
#pragma unroll
        for (int kk2 = 0; kk2 < 2; kk2++) {
            const int kk = ph * 2 + kk2;
            h8 nxtS[2], nxtD[2];
            if (kk < 7) {                        // prefetch next 16B slice
                const int c1 = (kk + 1) * 32;
#pragma unroll
                for (int mt = 0; mt < 2; mt++) {
                    nxtS[mt] = *(const h8*)(hq + (size_t)sidx[mt] * HIDN + c1);
                    nxtD[mt] = *(const h8*)(hq + (size_t)didx[mt] * HIDN + c1);
                }
            }
            const int ko = kk2 * 64 + q * 8;
            // half 0 (cols +0..3)
            {
                h8 a0[2];
#pragma unroll
                for (int mt = 0; mt < 2; mt++) {
#pragma unroll
                    for (int j = 0; j < 4; j++) {
                        float x1 = (float)curS[mt][j], x2 = (float)curD[mt][j];
                        a0[mt][2 * j]     = (_Float16)(x1 * x2);
                        a0[mt][2 * j + 1] = (_Float16)fabsf(x1 - x2);
                    }
                }
                h8 bf[4];
#pragma unroll
                for (int nt = 0; nt < 4; nt++)
                    bf[nt] = *(const h8*)&BtL[(nt * 16 + l15) * 136 + ko];
#pragma unroll
                for (int mt = 0; mt < 2; mt++)
#pragma unroll
                    for (int nt = 0; nt < 4; nt++)
                        acc[mt][nt] = __builtin_amdgcn_mfma_f32_16x16x32_f16(a0[mt], bf[nt], acc[mt][nt], 0, 0, 0);
            }
            // half 1 (cols +4..7)
            {
                h8 a1[2];
#pragma unroll
                for (int mt = 0; mt < 2; mt++) {
#pragma unroll
                    for (int j = 0; j < 4; j++) {
                        float x1 = (float)curS[mt][4 + j], x2 = (float)curD[mt][4 + j];
                        a1[mt][2 * j]     = (_Float16)(x1 * x2);
                        a1[mt][2 * j + 1] = (_Float16)fabsf(x1 - x2);
                    }
                }
                h8 bf[4];
#pragma unroll
                for (int nt = 0; nt < 4; nt++)
                    bf[nt] = *(const h8*)&BtL[(nt * 16 + l15) * 136 + ko + 32];
#pragma unroll
                for (int mt = 0; mt < 2; mt++)
#pragma unroll
                    for (int nt = 0; nt < 4; nt++)
                        acc[mt][nt] = __builtin_amdgcn_mfma_f32_16x16x32_f16(a1[mt], bf[nt], acc[mt][nt], 0, 0, 0);
            }
            if (kk < 7) {
#pragma unroll
                for (int mt = 0; mt < 2; mt++) { curS[mt] = nxtS[mt]; curD[mt] = nxtD[mt]; }
            }
        }
    }

    // struct features step (k' = 512..543, only 512/513 nonzero)
    __syncthreads();
    {
        const int r = tid & 63, ck = tid >> 6;
        *(h8*)&BtL[r * 136 + ck * 8] = *(const h8*)(BtG + (size_t)r * 544 + 512 + ck * 8);
    }
    __syncthreads();
    {
        h8 bf[4];
#pragma unroll
        for (int nt = 0; nt < 4; nt++)
            bf[nt] = *(const h8*)&BtL[(nt * 16 + l15) * 136 + q * 8];
#pragma unroll
        for (int mt = 0; mt < 2; mt++) {
            h8 a = (h8){0, 0, 0, 0, 0, 0, 0, 0};
            if (q == 0) {
                a[0] = (_Float16)(la[mt] + lb[mt]);
                a[1] = (_Float16)fabsf(la[mt] - lb[mt]);
            }
#pragma unroll
            for (int nt = 0; nt < 4; nt++)
                acc[mt][nt] = __builtin_amdgcn_mfma_f32_16x16x32_f16(a, bf[nt], acc[mt][nt], 0, 0, 0);
        }
    }

    float b1v[4], w2v[4];
#pragma unroll
    for (int nt = 0; nt < 4; nt++) {
        int col = nt * 16 + l15;
        b1v[nt] = eb1[col];
        w2v[nt] = ew2[col];
    }
    const float b2s = eb2[0];
    float part[2][4];
#pragma unroll
    for (int mt = 0; mt < 2; mt++)
#pragma unroll
        for (int reg = 0; reg < 4; reg++) {
            float s = 0.f;
#pragma unroll
            for (int nt = 0; nt < 4; nt++) {
                float v = acc[mt][nt][reg] + b1v[nt];
                s += fmaxf(v, 0.f) * w2v[nt];
            }
            part[mt][reg] = s;
        }
#pragma unroll
    for (int off = 1; off < 16; off <<= 1)
#pragma unroll
        for (int mt = 0; mt < 2; mt++)
#pragma unroll
            for (int reg = 0; reg < 4; reg++)
                part[mt][reg] += __shfl_xor(part[mt][reg], off, 64);
    if (l15 == 0) {
#pragma unroll
        for (int mt = 0; mt < 2; mt++)
#pragma unroll
            for (int reg = 0; reg < 4; reg++) {
                int er = eb + wid * 32 + mt * 16 + q * 4 + reg;
                if (er < E2P) {
                    float xr = part[mt][reg] + b2s;
                    wsym[er] = 0.8f / (1.0f + __expf(-xr));
                }
            }
    }
}

// ======== fused cooperative BP: m register-resident across all iterations ========

// symmetric K-product: f = m @ exp(w*Rs), 36 unique exps (Rs symmetric)
__device__ __forceinline__ void kprod(const float* __restrict__ RsL, float w,
                                      const float* me, const float* mr,
                                      float* fe, float* fr) {
#pragma unroll
    for (int d = 0; d < 8; d++) { fe[d] = 0.f; fr[d] = 0.f; }
#pragma unroll
    for (int c = 0; c < 8; c++) {
        {
            float kv = __expf(w * RsL[c * 8 + c]);
            fe[c] += me[c] * kv;
            fr[c] += mr[c] * kv;
        }
#pragma unroll
        for (int d = c + 1; d < 8; d++) {
            float kv = __expf(w * RsL[c * 8 + d]);
            fe[d] += me[c] * kv; fr[d] += mr[c] * kv;
            fe[c] += me[d] * kv; fr[c] += mr[d] * kv;
        }
    }
}

// CSR node-sum phase: 8 threads/node, h8 loads, shfl fold -> Z[n][8+j]
__device__ __forceinline__ void sum_phase(const _Float16* __restrict__ logfb,
        const int* __restrict__ base, const int* __restrict__ deg,
        float* __restrict__ Z, int gtid) {
    const int j = gtid & 7;
    const int lane = threadIdx.x & 63;
#pragma unroll
    for (int k = 0; k < 2; k++) {
        int g = gtid + k * TPT;
        int n = g >> 3;
        bool on = (n < NN);
        int b = 0, cnt = 0;
        if (on) { b = base[n]; cnt = deg[n]; }
        float acc[8];
#pragma unroll
        for (int d = 0; d < 8; d++) acc[d] = 0.f;
        for (int s = j; s < cnt; s += 8) {
            h8 v = *(const h8*)(logfb + (size_t)(b + s) * 8);
#pragma unroll
            for (int d = 0; d < 8; d++) acc[d] += (float)v[d];
        }
        float v4[4], v2[2], r;
        {
            bool hi = (lane & 4) != 0;
#pragma unroll
            for (int i = 0; i < 4; i++) {
                float send = hi ? acc[i] : acc[i + 4];
                float recv = __shfl_xor(send, 4, 64);
                v4[i] = (hi ? acc[i + 4] : acc[i]) + recv;
            }
        }
        {
            bool hi = (lane & 2) != 0;
#pragma unroll
            for (int i = 0; i < 2; i++) {
                float send = hi ? v4[i] : v4[i + 2];
                float recv = __shfl_xor(send, 2, 64);
                v2[i] = (hi ? v4[i + 2] : v4[i]) + recv;
            }
        }
        {
            bool hi = (lane & 1) != 0;
            float send = hi ? v2[0] : v2[1];
            float recv = __shfl_xor(send, 1, 64);
            r = (hi ? v2[1] : v2[0]) + recv;
        }
        if (on) Z[(size_t)n * 16 + 8 + j] = r;
    }
}

__global__ __launch_bounds__(256, 4) void k_bp(const int* __restrict__ ei,
        const float* __restrict__ wsymb, const float* __restrict__ degc,
        const float* __restrict__ Rs, float* __restrict__ Z,
        const int* __restrict__ pos, const int* __restrict__ base,
        const int* __restrict__ deg, _Float16* __restrict__ logfb,
        float* __restrict__ out) {
    cg::grid_group grid = cg::this_grid();
    __shared__ float RsL[64];
    const int tid = threadIdx.x;
    if (tid < 64) RsL[tid] = Rs[tid];
    __syncthreads();
    const float alpha = Rs[64];
    const int gtid = blockIdx.x * 256 + tid;

    // persistent per-pair state (2 pairs/thread)
    int sp[2], dp[2], pz0[2], pz1[2];
    float w[2], nrm[2];
    float me[2][8], mr[2][8];
    h8 lh0[2], lh1[2];            // carried log_f fragments (f16, incl. *nrm)
    bool act[2];
#pragma unroll
    for (int k = 0; k < 2; k++) {
        int p = gtid + k * TPT;
        act[k] = (p < E2P);
        int pp = act[k] ? p : 0;
        sp[k] = ei[pp]; dp[k] = ei[EDD + pp];
        w[k] = wsymb[pp];
        nrm[k] = rsqrtf(degc[sp[k]] * degc[dp[k]]);
        pz0[k] = pos[pp]; pz1[k] = pos[E2P + pp];
    }
    // ---- init: m = softmax(log_phi[src/dst]); write log_f(m0) ----
#pragma unroll
    for (int k = 0; k < 2; k++) {
        const f4* Zs = (const f4*)(Z + (size_t)sp[k] * 16);
        const f4* Zd = (const f4*)(Z + (size_t)dp[k] * 16);
        f4 ls0 = Zs[0], ls1 = Zs[1], ld0 = Zd[0], ld1 = Zd[1];
        float lps[8], lpd[8];
#pragma unroll
        for (int u = 0; u < 4; u++) { lps[u] = ls0[u]; lps[4+u] = ls1[u];
                                      lpd[u] = ld0[u]; lpd[4+u] = ld1[u]; }
        float mx = lps[0], mx2 = lpd[0];
#pragma unroll
        for (int d = 1; d < 8; d++) { mx = fmaxf(mx, lps[d]); mx2 = fmaxf(mx2, lpd[d]); }
        float s = 0.f, s2 = 0.f;
#pragma unroll
        for (int d = 0; d < 8; d++) { me[k][d] = __expf(lps[d] - mx); s += me[k][d];
                                      mr[k][d] = __expf(lpd[d] - mx2); s2 += mr[k][d]; }
        float rs = 1.f / s, rs2 = 1.f / s2;
#pragma unroll
        for (int d = 0; d < 8; d++) { me[k][d] *= rs; mr[k][d] *= rs2; }
        float fe[8], fr[8];
        kprod(RsL, w[k], me[k], mr[k], fe, fr);
#pragma unroll
        for (int d = 0; d < 8; d++) {
            lh0[k][d] = (_Float16)(__logf(fmaxf(fe[d], 1e-12f)) * nrm[k]);
            lh1[k][d] = (_Float16)(__logf(fmaxf(fr[d], 1e-12f)) * nrm[k]);
        }
        if (act[k]) {
            *(h8*)(logfb + (size_t)pz0[k] * 8) = lh0[k];
            *(h8*)(logfb + (size_t)pz1[k] * 8) = lh1[k];
        }
    }
    __threadfence();
    grid.sync();
    sum_phase(logfb, base, deg, Z, gtid);
    __threadfence();
    grid.sync();

    for (int t = 0; t < 10; t++) {
#pragma unroll
        for (int k = 0; k < 2; k++) {
            // carried log_f fragments (same f16 values the sum consumed -> exact exclusion)
            float lfe[8], lfr[8];
#pragma unroll
            for (int d = 0; d < 8; d++) { lfe[d] = (float)lh0[k][d]; lfr[d] = (float)lh1[k][d]; }
            const f4* Zs = (const f4*)(Z + (size_t)sp[k] * 16);
            const f4* Zd = (const f4*)(Z + (size_t)dp[k] * 16);
            f4 ls0 = Zs[0], ls1 = Zs[1], ss0 = Zs[2], ss1 = Zs[3];
            f4 ld0 = Zd[0], ld1 = Zd[1], sd0 = Zd[2], sd1 = Zd[3];
            float te[8], tr[8];
#pragma unroll
            for (int u = 0; u < 4; u++) {
                te[u]     = ls0[u] + alpha * (ss0[u] - lfr[u]);
                te[4 + u] = ls1[u] + alpha * (ss1[u] - lfr[4 + u]);
                tr[u]     = ld0[u] + alpha * (sd0[u] - lfe[u]);
                tr[4 + u] = ld1[u] + alpha * (sd1[u] - lfe[4 + u]);
            }
            float m1[8], m2[8];
            float mx = te[0], mx2 = tr[0];
#pragma unroll
            for (int d = 1; d < 8; d++) { mx = fmaxf(mx, te[d]); mx2 = fmaxf(mx2, tr[d]); }
            float s = 0.f, s2 = 0.f;
#pragma unroll
            for (int d = 0; d < 8; d++) { m1[d] = __expf(te[d] - mx);  s  += m1[d];
                                          m2[d] = __expf(tr[d] - mx2); s2 += m2[d]; }
            float rs = 1.f / s, rs2 = 1.f / s2;
            float t1 = 0.f, t2 = 0.f;
#pragma unroll
            for (int d = 0; d < 8; d++) {
                m1[d] = fmaxf(0.8f * me[k][d] + 0.2f * m1[d] * rs,  1e-12f); t1 += m1[d];
                m2[d] = fmaxf(0.8f * mr[k][d] + 0.2f * m2[d] * rs2, 1e-12f); t2 += m2[d];
            }
            float rt1 = 1.f / t1, rt2 = 1.f / t2;
#pragma unroll
            for (int d = 0; d < 8; d++) { me[k][d] = m1[d] * rt1; mr[k][d] = m2[d] * rt2; }
            // new log_f from updated m
            float fe[8], fr[8];
            kprod(RsL, w[k], me[k], mr[k], fe, fr);
#pragma unroll
            for (int d = 0; d < 8; d++) {
                lh0[k][d] = (_Float16)(__logf(fmaxf(fe[d], 1e-12f)) * nrm[k]);
                lh1[k][d] = (_Float16)(__logf(fmaxf(fr[d], 1e-12f)) * nrm[k]);
            }
            if (act[k]) {
                *(h8*)(logfb + (size_t)pz0[k] * 8) = lh0[k];
                *(h8*)(logfb + (size_t)pz1[k] * 8) = lh1[k];
            }
        }
        __threadfence();
        grid.sync();
        sum_phase(logfb, base, deg, Z, gtid);
        __threadfence();
        grid.sync();
    }
    // ---- beliefs = softmax(log_phi + alpha*S) ----
#pragma unroll
    for (int k = 0; k < 2; k++) {
        int g = gtid + k * TPT;
        int n = g >> 3, d = g & 7;
        bool on = (g < NN * 8);
        float v = on ? (Z[(size_t)n * 16 + d] + alpha * Z[(size_t)n * 16 + 8 + d]) : -1e30f;
        float mx = v;
        mx = fmaxf(mx, __shfl_xor(mx, 1, 64));
        mx = fmaxf(mx, __shfl_xor(mx, 2, 64));
        mx = fmaxf(mx, __shfl_xor(mx, 4, 64));
        float ex = __expf(v - mx);
        float s = ex;
        s += __shfl_xor(s, 1, 64); s += __shfl_xor(s, 2, 64); s += __shfl_xor(s, 4, 64);
        if (on) out[g] = ex / s;
    }
}

// ======== fallback path (non-cooperative), verified in previous rounds ========

__global__ __launch_bounds__(256) void k_init(const int* __restrict__ ei,
        const float* __restrict__ wsymb, const float* __restrict__ degc,
        const float* __restrict__ Rs, const float* __restrict__ Z,
        const int* __restrict__ pos, _Float16* __restrict__ m,
        float* __restrict__ enorm, _Float16* __restrict__ logf) {
    __shared__ float RsL[64];
    const int tid = threadIdx.x;
    if (tid < 64) RsL[tid] = Rs[tid];
    __syncthreads();
    int p = blockIdx.x * 256 + tid;
    if (p >= E2P) return;
    int sp = ei[p], dp = ei[EDD + p];
    float w = wsymb[p];
    float nrm = rsqrtf(degc[sp] * degc[dp]);
    enorm[p] = nrm;
    const f4* Zs = (const f4*)(Z + (size_t)sp * 16);
    const f4* Zd = (const f4*)(Z + (size_t)dp * 16);
    f4 ls0 = Zs[0], ls1 = Zs[1], ld0 = Zd[0], ld1 = Zd[1];
    float lps[8], lpd[8];
#pragma unroll
    for (int u = 0; u < 4; u++) { lps[u] = ls0[u]; lps[4+u] = ls1[u]; lpd[u] = ld0[u]; lpd[4+u] = ld1[u]; }
    float me[8], mr[8];
    {
        float mx = lps[0], mx2 = lpd[0];
#pragma unroll
        for (int d = 1; d < 8; d++) { mx = fmaxf(mx, lps[d]); mx2 = fmaxf(mx2, lpd[d]); }
        float s = 0.f, s2 = 0.f;
#pragma unroll
        for (int d = 0; d < 8; d++) { me[d] = __expf(lps[d] - mx); s += me[d];
                                      mr[d] = __expf(lpd[d] - mx2); s2 += mr[d]; }
        float rs = 1.f / s, rs2 = 1.f / s2;
#pragma unroll
        for (int d = 0; d < 8; d++) { me[d] *= rs; mr[d] *= rs2; }
    }
    {
        h8 mh, mh2;
#pragma unroll
        for (int d = 0; d < 8; d++) { mh[d] = (_Float16)me[d]; mh2[d] = (_Float16)mr[d]; }
        *(h8*)(m + (size_t)p * 8) = mh;
        *(h8*)(m + (size_t)(E2P + p) * 8) = mh2;
    }
    float fe[8], fr[8];
    kprod(RsL, w, me, mr, fe, fr);
    h8 le, lr;
#pragma unroll
    for (int d = 0; d < 8; d++) {
        le[d] = (_Float16)(__logf(fmaxf(fe[d], 1e-12f)) * nrm);
        lr[d] = (_Float16)(__logf(fmaxf(fr[d], 1e-12f)) * nrm);
    }
    *(h8*)(logf + (size_t)pos[p] * 8)       = le;
    *(h8*)(logf + (size_t)pos[E2P + p] * 8) = lr;
}

__global__ __launch_bounds__(256) void k_bpF(const int* __restrict__ ei,
        const float* __restrict__ wsymb, const float* __restrict__ enorm,
        const float* __restrict__ Rs, const float* __restrict__ Z,
        const int* __restrict__ pos, const _Float16* __restrict__ m,
        _Float16* __restrict__ mo, _Float16* __restrict__ logf) {
    __shared__ float RsL[64];
    const int tid = threadIdx.x;
    if (tid < 64) RsL[tid] = Rs[tid];
    __syncthreads();
    int p = blockIdx.x * 256 + tid;
    if (p >= E2P) return;
    int sp = ei[p], dp = ei[EDD + p];
    float w = wsymb[p], nrm = enorm[p];
    const float alpha = Rs[64];
    h8 mhe = *(const h8*)(m + (size_t)p * 8);
    h8 mhr = *(const h8*)(m + (size_t)(E2P + p) * 8);
    float me[8], mr[8];
#pragma unroll
    for (int d = 0; d < 8; d++) { me[d] = (float)mhe[d]; mr[d] = (float)mhr[d]; }
    float fe[8], fr[8];
    kprod(RsL, w, me, mr, fe, fr);
    float lfe[8], lfr[8];
#pragma unroll
    for (int d = 0; d < 8; d++) {
        lfe[d] = __logf(fmaxf(fe[d], 1e-12f)) * nrm;
        lfr[d] = __logf(fmaxf(fr[d], 1e-12f)) * nrm;
    }
    const f4* Zs = (const f4*)(Z + (size_t)sp * 16);
    const f4* Zd = (const f4*)(Z + (size_t)dp * 16);
    f4 ls0 = Zs[0], ls1 = Zs[1], ss0 = Zs[2], ss1 = Zs[3];
    f4 ld0 = Zd[0], ld1 = Zd[1], sd0 = Zd[2], sd1 = Zd[3];
    float te[8], tr[8];
#pragma unroll
    for (int u = 0; u < 4; u++) {
        te[u]     = ls0[u] + alpha * (ss0[u] - lfr[u]);
        te[4 + u] = ls1[u] + alpha * (ss1[u] - lfr[4 + u]);
        tr[u]     = ld0[u] + alpha * (sd0[u] - lfe[u]);
        tr[4 + u] = ld1[u] + alpha * (sd1[u] - lfe[4 + u]);
    }
    float m1[8], m2[8];
    {
        float mx = te[0], mx2 = tr[0];
#pragma unroll
        for (int d = 1; d < 8; d++) { mx = fmaxf(mx, te[d]); mx2 = fmaxf(mx2, tr[d]); }
        float s = 0.f, s2 = 0.f;
#pragma unroll
        for (int d = 0; d < 8; d++) { m1[d] = __expf(te[d] - mx); s += m1[d];
                                      m2[d] = __expf(tr[d] - mx2); s2 += m2[d]; }
        float rs = 1.f / s, rs2 = 1.f / s2;
        float t1 = 0.f, t2 = 0.f;
#pragma unroll
        for (int d = 0; d < 8; d++) {
            m1[d] = fmaxf(0.8f * me[d] + 0.2f * m1[d] * rs, 1e-12f);  t1 += m1[d];
            m2[d] = fmaxf(0.8f * mr[d] + 0.2f * m2[d] * rs2, 1e-12f); t2 += m2[d];
        }
        float rt1 = 1.f / t1, rt2 = 1.f / t2;
#pragma unroll
        for (int d = 0; d < 8; d++) { m1[d] *= rt1; m2[d] *= rt2; }
    }
    {
        h8 mh, mh2;
#pragma unroll
        for (int d = 0; d < 8; d++) { mh[d] = (_Float16)m1[d]; mh2[d] = (_Float16)m2[d]; }
        *(h8*)(mo + (size_t)p * 8) = mh;
        *(h8*)(mo + (size_t)(E2P + p) * 8) = mh2;
    }
    float fe2[8], fr2[8];
    kprod(RsL, w, m1, m2, fe2, fr2);
    h8 le, lr;
#pragma unroll
    for (int d = 0; d < 8; d++) {
        le[d] = (_Float16)(__logf(fmaxf(fe2[d], 1e-12f)) * nrm);
        lr[d] = (_Float16)(__logf(fmaxf(fr2[d], 1e-12f)) * nrm);
    }
    *(h8*)(logf + (size_t)pos[p] * 8)       = le;
    *(h8*)(logf + (size_t)pos[E2P + p] * 8) = lr;
}

__global__ void k_sum(const _Float16* __restrict__ logf, const int* __restrict__ base,
                      const int* __restrict__ deg, float* __restrict__ Z) {
    int g = blockIdx.x * 256 + threadIdx.x;
    int n = g >> 3;
    if (n >= NN) return;
    int j = threadIdx.x & 7;
    int b = base[n], cnt = deg[n];
    float acc[8];
#pragma unroll
    for (int d = 0; d < 8; d++) acc[d] = 0.f;
    for (int s = j; s < cnt; s += 8) {
        h8 v = *(const h8*)(logf + (size_t)(b + s) * 8);
#pragma unroll
        for (int d = 0; d < 8; d++) acc[d] += (float)v[d];
    }
    int lane = threadIdx.x & 63;
    float v4[4], v2[2], r;
    {
        bool hi = (lane & 4) != 0;
#pragma unroll
        for (int i = 0; i < 4; i++) {
            float send = hi ? acc[i] : acc[i + 4];
            float recv = __shfl_xor(send, 4, 64);
            v4[i] = (hi ? acc[i + 4] : acc[i]) + recv;
        }
    }
    {
        bool hi = (lane & 2) != 0;
#pragma unroll
        for (int i = 0; i < 2; i++) {
            float send = hi ? v4[i] : v4[i + 2];
            float recv = __shfl_xor(send, 2, 64);
            v2[i] = (hi ? v4[i + 2] : v4[i]) + recv;
        }
    }
    {
        bool hi = (lane & 1) != 0;
        float send = hi ? v2[0] : v2[1];
        float recv = __shfl_xor(send, 1, 64);
        r = (hi ? v2[1] : v2[0]) + recv;
    }
    Z[(size_t)n * 16 + 8 + j] = r;
}

__global__ void k_bel(const float* __restrict__ Z, const float* __restrict__ Rs,
                      float* __restrict__ out) {
    int tid = blockIdx.x * 256 + threadIdx.x;
    if (tid >= NN * 8) return;
    int n = tid >> 3, d = tid & 7;
    float alpha = Rs[64];
    float v = Z[(size_t)n * 16 + d] + alpha * Z[(size_t)n * 16 + 8 + d];
    float mx = v;
    mx = fmaxf(mx, __shfl_xor(mx, 1, 64));
    mx = fmaxf(mx, __shfl_xor(mx, 2, 64));
    mx = fmaxf(mx, __shfl_xor(mx, 4, 64));
    float ex = __expf(v - mx);
    float s = ex;
    s += __shfl_xor(s, 1, 64); s += __shfl_xor(s, 2, 64); s += __shfl_xor(s, 4, 64);
    out[tid] = ex / s;
}

extern "C" void kernel_launch(void* const* d_in, const int* in_sizes, int n_in,
                              void* d_out, int out_size, void* d_ws, size_t ws_size,
                              hipStream_t stream) {
    if (ws_size < WS_NEED) return;
    const float* x        = (const float*)d_in[0];
    const int*   ei       = (const int*)d_in[1];
    const float* enc_w1   = (const float*)d_in[3];
    const float* enc_b1   = (const float*)d_in[4];
    const float* enc_w2   = (const float*)d_in[5];
    const float* enc_b2   = (const float*)d_in[6];
    const float* edge_w1  = (const float*)d_in[7];
    const float* edge_b1  = (const float*)d_in[8];
    const float* edge_w2  = (const float*)d_in[9];
    const float* edge_b2  = (const float*)d_in[10];
    const float* R_raw    = (const float*)d_in[11];
    const float* Rsl      = (const float*)d_in[12];
    const float* mlog     = (const float*)d_in[13];

    char* ws = (char*)d_ws;
    _Float16* hf     = (_Float16*)(ws + OFF_HF16);
    _Float16* logfb  = (_Float16*)(ws + OFF_LOGF);
    float* Zb        = (float*)(ws + OFF_Z);
    int*   deg       = (int*)  (ws + OFF_DEG);
    float* logdeg    = (float*)(ws + OFF_LOGDEG);
    float* degc      = (float*)(ws + OFF_DEGC);
    int*   baseA     = (int*)  (ws + OFF_BASE);
    int*   cnt       = (int*)  (ws + OFF_CNT);
    int*   blk       = (int*)  (ws + OFF_BLK);
    _Float16* Wt     = (_Float16*)(ws + OFF_WT);
    _Float16* Bt     = (_Float16*)(ws + OFF_BT);
    float* Rs        = (float*)(ws + OFF_RS);
    float* wsym      = (float*)(ws + OFF_WSYM);
    float* enorm     = (float*)(ws + OFF_ENORM);
    int*   pos       = (int*)  (ws + OFF_POS);
    _Float16* mA     = (_Float16*)(ws + OFF_MA);
    _Float16* mB     = (_Float16*)(ws + OFF_MB);
    float* outp      = (float*)d_out;

    hipMemsetAsync(deg, 0, (size_t)NN * 4, stream);
    k_deg<<<dim3(EDD / 256), dim3(256), 0, stream>>>(ei, deg);
    k_node<<<dim3(NBLK), dim3(256), 0, stream>>>(deg, logdeg, degc);
    k_prep<<<dim3((256 * 512 + 64 * 544 + 65 + 255) / 256), dim3(256), 0, stream>>>(
        enc_w1, edge_w1, R_raw, Rsl, mlog, Wt, Bt, Rs);
    // CSR build (one-time)
    k_scan1<<<dim3(NBLK), dim3(256), 0, stream>>>(deg, cnt /*incl scratch*/, blk);
    k_scan2<<<dim3(1), dim3(256), 0, stream>>>(blk);
    k_scan3<<<dim3(NBLK), dim3(256), 0, stream>>>(cnt, deg, blk, baseA);
    hipMemsetAsync(cnt, 0, (size_t)NN * 4, stream);
    k_pos<<<dim3(EDD / 256), dim3(256), 0, stream>>>(ei, baseA, cnt, pos);
    // encoder + edge MLP
    k_enc<<<dim3((NN + 63) / 64), dim3(256), 0, stream>>>(x, Wt, enc_b1, hf);
    k_logits<<<dim3(NBLK), dim3(256), 0, stream>>>(hf, enc_w2, enc_b2, Zb);
    k_edge<<<dim3(E2P / 128), dim3(256), 0, stream>>>(ei, hf, logdeg, Bt, edge_b1,
                                                      edge_w2, edge_b2, wsym);
    // fused cooperative BP loop (logfb aliases hf — hf is dead from here on)
    {
        const int* eiA = ei; const float* wsA = wsym; const float* dcA = degc;
        const float* RsA = Rs; float* ZA = Zb; const int* posA2 = pos;
        const int* bA = baseA; const int* dgA = deg; _Float16* lfA = logfb;
        float* outA = outp;
        void* args[] = { (void*)&eiA, (void*)&wsA, (void*)&dcA, (void*)&RsA,
                         (void*)&ZA, (void*)&posA2, (void*)&bA, (void*)&dgA,
                         (void*)&lfA, (void*)&outA };
        hipError_t cerr = hipLaunchCooperativeKernel((void*)k_bp, dim3(NBP), dim3(256),
                                                     args, 0, stream);
        if (cerr != hipSuccess) {
            // fallback: verified multi-kernel path
            k_init<<<dim3((E2P + 255) / 256), dim3(256), 0, stream>>>(ei, wsym, degc, Rs,
                                                                      Zb, pos, mA, enorm, logfb);
            k_sum<<<dim3((NN * 8 + 255) / 256), dim3(256), 0, stream>>>(logfb, baseA, deg, Zb);
            _Float16* mc = mA; _Float16* mn = mB;
            for (int t = 0; t < 10; t++) {
                k_bpF<<<dim3((E2P + 255) / 256), dim3(256), 0, stream>>>(ei, wsym, enorm, Rs,
                                                                         Zb, pos, mc, mn, logfb);
                k_sum<<<dim3((NN * 8 + 255) / 256), dim3(256), 0, stream>>>(logfb, baseA, deg, Zb);
                _Float16* tm = mc; mc = mn; mn = tm;
            }
            k_bel<<<dim3((NN * 8 + 255) / 256), dim3(256), 0, stream>>>(Zb, Rs, outp);
        }
    }
    (void)in_sizes; (void)n_in; (void)out_size;
}

// Round 3
// 798.741 us; speedup vs baseline: 5.3429x; 5.3429x over previous
//
#include <hip/hip_runtime.h>
#include <cstddef>
#include <cstdint>

typedef _Float16 h4 __attribute__((ext_vector_type(4)));
typedef _Float16 h8 __attribute__((ext_vector_type(8)));
typedef float    f4 __attribute__((ext_vector_type(4)));
typedef int      i4 __attribute__((ext_vector_type(4)));

#define NN      50000
#define IND     512
#define HIDN    256
#define E2P     400000
#define EDD     800000
#define NBLK    196   // ceil(NN/256)
#define EBLK    1563  // ceil(E2P/256)

// ---- workspace layout (bytes) ----
// logf (f16 [EDD][8] = 12.8MB) aliases hf (dead after k_edge)
#define OFF_HF16    ((size_t)0)            // 25,600,000  f16 h [NN][256]
#define OFF_LOGF    ((size_t)0)            // 12,800,000  f16 [EDD][8] (CSR order)
#define OFF_Z       ((size_t)25600000)     //  3,200,000  f32 [NN][16]: [0:8]=log_phi, [8:16]=S
#define OFF_DEG     ((size_t)28800000)     //    200,000  int
#define OFF_LOGDEG  ((size_t)29000000)     //    200,000  f32
#define OFF_DEGC    ((size_t)29200000)     //    200,000  f32
#define OFF_BASE    ((size_t)29400000)     //    200,000  int (CSR exclusive scan)
#define OFF_CNT     ((size_t)29600000)     //    200,000  int (scan scratch / fill counters)
#define OFF_BLK     ((size_t)29800000)     //      4,096  int (scan block sums)
#define OFF_WT      ((size_t)29804096)     //    262,144  f16 enc_w1^T
#define OFF_BT      ((size_t)30066240)     //     69,632  f16 edge_w1 perm^T (h8-gather K-order)
#define OFF_RS      ((size_t)30135872)     //        512  f32 Rs[64] + alpha at [64]
#define OFF_WSYM    ((size_t)30136384)     //  1,600,000  f32 [E2P] (original pair order)
#define OFF_POS     ((size_t)31736384)     //  3,200,000  int [EDD] CSR slot of each directed edge
#define OFF_ORDER   ((size_t)34936384)     //  1,600,000  int [E2P] pairs sorted by src
#define OFF_BASE2   ((size_t)36536384)     //    200,000  int (pair-CSR by src)
#define OFF_OFS2    ((size_t)36736384)     //    200,000  int (counters)
#define OFF_PRC     ((size_t)36936384)     //  6,400,000  int4 [E2P] {sp,dp,pz0,pz1} sorted
#define OFF_WN      ((size_t)43336384)     //  3,200,000  float2 [E2P] {w,nrm} sorted
#define OFF_M       ((size_t)46536384)     // 12,800,000  f16 [E2P][16] packed m (in-place)
#define WS_NEED     ((size_t)59336384)

// ---------------- degree count ----------------
__global__ void k_deg(const int* __restrict__ ei, int* __restrict__ deg) {
    int e = blockIdx.x * 256 + threadIdx.x;   // grid exact: EDD
    atomicAdd(&deg[ei[e]], 1);
}

__global__ void k_node(const int* __restrict__ deg, float* __restrict__ logdeg,
                       float* __restrict__ degc) {
    int n = blockIdx.x * 256 + threadIdx.x;
    if (n < NN) {
        float d = (float)deg[n];
        logdeg[n] = logf(d + 1.0f);
        degc[n]   = fmaxf(d, 1.0f);
    }
}

// ---------------- generic NN-sized prefix-sum (3 tiny kernels) ----------------
__global__ void k_scan1(const int* __restrict__ deg, int* __restrict__ incl,
                        int* __restrict__ blk) {
    __shared__ int sm[256];
    int i = blockIdx.x * 256 + threadIdx.x;
    int v = (i < NN) ? deg[i] : 0;
    sm[threadIdx.x] = v;
    __syncthreads();
    for (int off = 1; off < 256; off <<= 1) {
        int t = (threadIdx.x >= off) ? sm[threadIdx.x - off] : 0;
        __syncthreads();
        sm[threadIdx.x] += t;
        __syncthreads();
    }
    if (i < NN) incl[i] = sm[threadIdx.x];
    if (threadIdx.x == 255) blk[blockIdx.x] = sm[255];
}

__global__ void k_scan2(int* __restrict__ blk) {
    __shared__ int sm[256];
    int v = (threadIdx.x < NBLK) ? blk[threadIdx.x] : 0;
    sm[threadIdx.x] = v;
    __syncthreads();
    for (int off = 1; off < 256; off <<= 1) {
        int t = (threadIdx.x >= off) ? sm[threadIdx.x - off] : 0;
        __syncthreads();
        sm[threadIdx.x] += t;
        __syncthreads();
    }
    if (threadIdx.x < NBLK) blk[threadIdx.x] = sm[threadIdx.x];
}

__global__ void k_scan3(const int* __restrict__ incl, const int* __restrict__ deg,
                        const int* __restrict__ blk, int* __restrict__ base) {
    int i = blockIdx.x * 256 + threadIdx.x;
    if (i < NN) {
        int off = (blockIdx.x > 0) ? blk[blockIdx.x - 1] : 0;
        base[i] = off + incl[i] - deg[i];
    }
}

// pos[e] = CSR slot of directed edge e within its dst node's segment
__global__ void k_pos(const int* __restrict__ ei, const int* __restrict__ base,
                      int* __restrict__ cnt, int* __restrict__ pos) {
    int e = blockIdx.x * 256 + threadIdx.x;   // grid exact: EDD
    int dstn = ei[EDD + e];
    pos[e] = base[dstn] + atomicAdd(&cnt[dstn], 1);
}

// ---- pair counting-sort by src: cnt -> scan -> fill ----
__global__ void k_cnt2(const int* __restrict__ ei, int* __restrict__ cnt2) {
    int p = blockIdx.x * 256 + threadIdx.x;
    if (p < E2P) atomicAdd(&cnt2[ei[p]], 1);
}

__global__ void k_order(const int* __restrict__ ei, const int* __restrict__ base2,
                        int* __restrict__ ofs2, int* __restrict__ order) {
    int p = blockIdx.x * 256 + threadIdx.x;
    if (p < E2P) {
        int s = ei[p];
        order[base2[s] + atomicAdd(&ofs2[s], 1)] = p;
    }
}

// ---------------- weight prep ----------------
// Bt K-order for h8 gathers: MFMA step tm (0..15), lane q, element e=2j+typ
//   k' = tm*32 + q*8 + 2j + typ  <->  column c = (tm>>1)*32 + q*8 + (tm&1)*4 + j
//   typ 0 = product feature (row c), typ 1 = absdiff (row 256+c). k'=512,513: struct.
__global__ void k_prep(const float* __restrict__ enc_w1, const float* __restrict__ edge_w1,
                       const float* __restrict__ R_raw, const float* __restrict__ Rsl,
                       const float* __restrict__ mlog,
                       _Float16* __restrict__ Wt, _Float16* __restrict__ Bt,
                       float* __restrict__ Rs) {
    int gid = blockIdx.x * 256 + threadIdx.x;
    if (gid < 256 * 512) {                       // Wt[n][k] = enc_w1[k][n]
        int n = gid >> 9, k = gid & 511;
        Wt[n * 512 + k] = (_Float16)enc_w1[k * 256 + n];
        return;
    }
    int g2 = gid - 256 * 512;
    if (g2 < 64 * 544) {                         // Bt[n][k'] with h8-gather K perm
        int n = g2 / 544, k = g2 - n * 544;
        float v = 0.0f;
        if (k < 512) {
            int tm = k >> 5, r = k & 31;
            int qq = r >> 3, jj = (r >> 1) & 3, typ = k & 1;
            int c = (tm >> 1) * 32 + qq * 8 + (tm & 1) * 4 + jj;
            v = edge_w1[(typ ? 256 + c : c) * 64 + n];
        } else if (k < 514) {
            v = edge_w1[k * 64 + n];
        }
        Bt[n * 544 + k] = (_Float16)v;
        return;
    }
    int g3 = g2 - 64 * 544;
    if (g3 < 64) {
        int c = g3 >> 3, d = g3 & 7;
        float rv = 0.5f * (R_raw[c * 8 + d] + R_raw[d * 8 + c]);
        float s  = log1pf(expf(Rsl[0])) + 1e-6f;
        Rs[g3] = s * tanhf(rv);
        return;
    }
    if (g3 == 64) {
        Rs[64] = 1.5f / (1.0f + expf(-mlog[0]));
    }
}

// ---------------- encoder layer 1: h = relu(x @ enc_w1 + b1), f16 MFMA ----------------
__global__ __launch_bounds__(256) void k_enc(const float* __restrict__ x,
                                             const _Float16* __restrict__ Wt,
                                             const float* __restrict__ b1,
                                             _Float16* __restrict__ hf) {
    __shared__ _Float16 XL[64 * 40];
    __shared__ _Float16 WL[256 * 40];
    const int tid = threadIdx.x;
    const int wid = tid >> 6;
    const int lane = tid & 63;
    const int l15 = lane & 15;
    const int q = lane >> 4;
    const int m0 = blockIdx.x * 64;

    f4 acc[16];
#pragma unroll
    for (int i = 0; i < 16; i++) acc[i] = (f4){0.f, 0.f, 0.f, 0.f};

    const int xr = tid >> 2;
    const int xs = tid & 3;
    const int gr = m0 + xr;

    for (int kt = 0; kt < 16; kt++) {
        __syncthreads();
        f4 xv0 = (f4){0, 0, 0, 0}, xv1 = (f4){0, 0, 0, 0};
        if (gr < NN) {
            const f4* xp = (const f4*)(x + (size_t)gr * IND + kt * 32 + xs * 8);
            xv0 = xp[0]; xv1 = xp[1];
        }
        h8 xh;
#pragma unroll
        for (int u = 0; u < 4; u++) { xh[u] = (_Float16)xv0[u]; xh[4 + u] = (_Float16)xv1[u]; }
        *(h8*)&XL[xr * 40 + xs * 8] = xh;
#pragma unroll
        for (int rep = 0; rep < 4; rep++) {
            int cid = rep * 256 + tid;
            int n = cid >> 2;
            int off = (cid & 3) * 8;
            h8 wv = *(const h8*)(Wt + (size_t)n * IND + kt * 32 + off);
            *(h8*)&WL[n * 40 + off] = wv;
        }
        __syncthreads();
        h8 a = *(const h8*)&XL[(wid * 16 + l15) * 40 + q * 8];
#pragma unroll
        for (int nt = 0; nt < 16; nt++) {
            h8 b = *(const h8*)&WL[(nt * 16 + l15) * 40 + q * 8];
            acc[nt] = __builtin_amdgcn_mfma_f32_16x16x32_f16(a, b, acc[nt], 0, 0, 0);
        }
    }
#pragma unroll
    for (int nt = 0; nt < 16; nt++) {
        int col = nt * 16 + l15;
        float bv = b1[col];
#pragma unroll
        for (int reg = 0; reg < 4; reg++) {
            int row = m0 + wid * 16 + q * 4 + reg;
            if (row < NN) {
                float v = acc[nt][reg] + bv;
                hf[(size_t)row * HIDN + col] = (_Float16)fmaxf(v, 0.f);
            }
        }
    }
}

// ---------------- encoder layer 2 + log_softmax -> Z[n][0:8] ----------------
__global__ void k_logits(const _Float16* __restrict__ hf, const float* __restrict__ w2,
                         const float* __restrict__ b2, float* __restrict__ Z) {
    __shared__ float w2L[2048];
    for (int i = threadIdx.x; i < 2048; i += 256) w2L[i] = w2[i];
    __syncthreads();
    int n = blockIdx.x * 256 + threadIdx.x;
    if (n >= NN) return;
    float sum[8];
#pragma unroll
    for (int c = 0; c < 8; c++) sum[c] = b2[c];
    for (int kb = 0; kb < 32; kb++) {
        h8 hv = *(const h8*)(hf + (size_t)n * HIDN + kb * 8);
#pragma unroll
        for (int u = 0; u < 8; u++) {
            float hx = (float)hv[u];
            const float* wr = &w2L[(kb * 8 + u) * 8];
#pragma unroll
            for (int c = 0; c < 8; c++) sum[c] += hx * wr[c];
        }
    }
    float mx = sum[0];
#pragma unroll
    for (int c = 1; c < 8; c++) mx = fmaxf(mx, sum[c]);
    float se = 0.f;
#pragma unroll
    for (int c = 0; c < 8; c++) se += __expf(sum[c] - mx);
    float lse = __logf(se);
#pragma unroll
    for (int c = 0; c < 8; c++) Z[(size_t)n * 16 + c] = sum[c] - mx - lse;
}

// ---------------- edge MLP: mt=2, 2x blocks for occupancy; h8 gathers + prefetch ------
__global__ __launch_bounds__(256) void k_edge(const int* __restrict__ ei,
        const _Float16* __restrict__ hf, const float* __restrict__ logdeg,
        const _Float16* __restrict__ BtG, const float* __restrict__ eb1,
        const float* __restrict__ ew2, const float* __restrict__ eb2,
        float* __restrict__ wsym) {
    __shared__ _Float16 BtL[64 * 136];
    const int tid = threadIdx.x;
    const int wid = tid >> 6;
    const int lane = tid & 63;
    const int l15 = lane & 15;
    const int q = lane >> 4;
    const int eb = blockIdx.x * 128;             // grid exact: E2P/128 = 3125

    int sidx[2], didx[2];
    float la[2], lb[2];
#pragma unroll
    for (int mt = 0; mt < 2; mt++) {
        int e = eb + wid * 32 + mt * 16 + l15;   // always < E2P
        sidx[mt] = ei[e];
        didx[mt] = ei[EDD + e];
        la[mt] = logdeg[sidx[mt]];
        lb[mt] = logdeg[didx[mt]];
    }

    f4 acc[2][4];
#pragma unroll
    for (int a = 0; a < 2; a++)
#pragma unroll
        for (int b = 0; b < 4; b++) acc[a][b] = (f4){0.f, 0.f, 0.f, 0.f};

    const _Float16* hq = hf + q * 8;            // lane's 16B column slice
    h8 curS[2], curD[2];
#pragma unroll
    for (int mt = 0; mt < 2; mt++) {            // kk=0 fragments (cols q*8..q*8+7)
        curS[mt] = *(const h8*)(hq + (size_t)sidx[mt] * HIDN);
        curD[mt] = *(const h8*)(hq + (size_t)didx[mt] * HIDN);
    }

    for (int ph = 0; ph < 4; ph++) {
        __syncthreads();
        {   // stage 64 rows x 128 cols of Bt
            const int r = tid & 63;
            const int cb = tid >> 6;
            const int kbase = ph * 128;
#pragma unroll
            for (int i = 0; i < 4; i++) {
                int ck = cb + i * 4;
                *(h8*)&BtL[r * 136 + ck * 8] =
                    *(const h8*)(BtG + (size_t)r * 544 + kbase + ck * 8);
            }
        }
        __syncthreads();
#pragma unroll
        for (int kk2 = 0; kk2 < 2; kk2++) {
            const int kk = ph * 2 + kk2;
            h8 nxtS[2], nxtD[2];
            if (kk < 7) {                        // prefetch next 16B slice
                const int c1 = (kk + 1) * 32;
#pragma unroll
                for (int mt = 0; mt < 2; mt++) {
                    nxtS[mt] = *(const h8*)(hq + (size_t)sidx[mt] * HIDN + c1);
                    nxtD[mt] = *(const h8*)(hq + (size_t)didx[mt] * HIDN + c1);
                }
            }
            const int ko = kk2 * 64 + q * 8;
            // half 0 (cols +0..3)
            {
                h8 a0[2];
#pragma unroll
                for (int mt = 0; mt < 2; mt++) {
#pragma unroll
                    for (int j = 0; j < 4; j++) {
                        float x1 = (float)curS[mt][j], x2 = (float)curD[mt][j];
                        a0[mt][2 * j]     = (_Float16)(x1 * x2);
                        a0[mt][2 * j + 1] = (_Float16)fabsf(x1 - x2);
                    }
                }
                h8 bf[4];
#pragma unroll
                for (int nt = 0; nt < 4; nt++)
                    bf[nt] = *(const h8*)&BtL[(nt * 16 + l15) * 136 + ko];
#pragma unroll
                for (int mt = 0; mt < 2; mt++)
#pragma unroll
                    for (int nt = 0; nt < 4; nt++)
                        acc[mt][nt] = __builtin_amdgcn_mfma_f32_16x16x32_f16(a0[mt], bf[nt], acc[mt][nt], 0, 0, 0);
            }
            // half 1 (cols +4..7)
            {
                h8 a1[2];
#pragma unroll
                for (int mt = 0; mt < 2; mt++) {
#pragma unroll
                    for (int j = 0; j < 4; j++) {
                        float x1 = (float)curS[mt][4 + j], x2 = (float)curD[mt][4 + j];
                        a1[mt][2 * j]     = (_Float16)(x1 * x2);
                        a1[mt][2 * j + 1] = (_Float16)fabsf(x1 - x2);
                    }
                }
                h8 bf[4];
#pragma unroll
                for (int nt = 0; nt < 4; nt++)
                    bf[nt] = *(const h8*)&BtL[(nt * 16 + l15) * 136 + ko + 32];
#pragma unroll
                for (int mt = 0; mt < 2; mt++)
#pragma unroll
                    for (int nt = 0; nt < 4; nt++)
                        acc[mt][nt] = __builtin_amdgcn_mfma_f32_16x16x32_f16(a1[mt], bf[nt], acc[mt][nt], 0, 0, 0);
            }
            if (kk < 7) {
#pragma unroll
                for (int mt = 0; mt < 2; mt++) { curS[mt] = nxtS[mt]; curD[mt] = nxtD[mt]; }
            }
        }
    }

    // struct features step (k' = 512..543, only 512/513 nonzero)
    __syncthreads();
    {
        const int r = tid & 63, ck = tid >> 6;
        *(h8*)&BtL[r * 136 + ck * 8] = *(const h8*)(BtG + (size_t)r * 544 + 512 + ck * 8);
    }
    __syncthreads();
    {
        h8 bf[4];
#pragma unroll
        for (int nt = 0; nt < 4; nt++)
            bf[nt] = *(const h8*)&BtL[(nt * 16 + l15) * 136 + q * 8];
#pragma unroll
        for (int mt = 0; mt < 2; mt++) {
            h8 a = (h8){0, 0, 0, 0, 0, 0, 0, 0};
            if (q == 0) {
                a[0] = (_Float16)(la[mt] + lb[mt]);
                a[1] = (_Float16)fabsf(la[mt] - lb[mt]);
            }
#pragma unroll
            for (int nt = 0; nt < 4; nt++)
                acc[mt][nt] = __builtin_amdgcn_mfma_f32_16x16x32_f16(a, bf[nt], acc[mt][nt], 0, 0, 0);
        }
    }

    float b1v[4], w2v[4];
#pragma unroll
    for (int nt = 0; nt < 4; nt++) {
        int col = nt * 16 + l15;
        b1v[nt] = eb1[col];
        w2v[nt] = ew2[col];
    }
    const float b2s = eb2[0];
    float part[2][4];
#pragma unroll
    for (int mt = 0; mt < 2; mt++)
#pragma unroll
        for (int reg = 0; reg < 4; reg++) {
            float s = 0.f;
#pragma unroll
            for (int nt = 0; nt < 4; nt++) {
                float v = acc[mt][nt][reg] + b1v[nt];
                s += fmaxf(v, 0.f) * w2v[nt];
            }
            part[mt][reg] = s;
        }
#pragma unroll
    for (int off = 1; off < 16; off <<= 1)
#pragma unroll
        for (int mt = 0; mt < 2; mt++)
#pragma unroll
            for (int reg = 0; reg < 4; reg++)
                part[mt][reg] += __shfl_xor(part[mt][reg], off, 64);
    if (l15 == 0) {
#pragma unroll
        for (int mt = 0; mt < 2; mt++)
#pragma unroll
            for (int reg = 0; reg < 4; reg++) {
                int er = eb + wid * 32 + mt * 16 + q * 4 + reg;
                if (er < E2P) {
                    float xr = part[mt][reg] + b2s;
                    wsym[er] = 0.8f / (1.0f + __expf(-xr));
                }
            }
    }
}

// ======== BP: pairs processed in src-sorted order; packed per-pair state ========

// symmetric K-product: f = m @ exp(w*Rs), 36 unique exps (Rs symmetric)
__device__ __forceinline__ void kprod(const float* __restrict__ RsL, float w,
                                      const float* me, const float* mr,
                                      float* fe, float* fr) {
#pragma unroll
    for (int d = 0; d < 8; d++) { fe[d] = 0.f; fr[d] = 0.f; }
#pragma unroll
    for (int c = 0; c < 8; c++) {
        {
            float kv = __expf(w * RsL[c * 8 + c]);
            fe[c] += me[c] * kv;
            fr[c] += mr[c] * kv;
        }
#pragma unroll
        for (int d = c + 1; d < 8; d++) {
            float kv = __expf(w * RsL[c * 8 + d]);
            fe[d] += me[c] * kv; fr[d] += mr[c] * kv;
            fe[c] += me[d] * kv; fr[c] += mr[d] * kv;
        }
    }
}

// init (sorted index i): gather originals via order[], write packed state + m + logf
__global__ __launch_bounds__(256) void k_init(const int* __restrict__ ei,
        const float* __restrict__ wsymb, const float* __restrict__ degc,
        const float* __restrict__ Rs, const float* __restrict__ Z,
        const int* __restrict__ pos, const int* __restrict__ order,
        i4* __restrict__ prc, float2* __restrict__ wn,
        _Float16* __restrict__ M, _Float16* __restrict__ logf) {
    __shared__ float RsL[64];
    const int tid = threadIdx.x;
    if (tid < 64) RsL[tid] = Rs[tid];
    __syncthreads();
    int i = blockIdx.x * 256 + tid;
    if (i >= E2P) return;
    int p = order[i];
    int sp = ei[p], dp = ei[EDD + p];
    float w = wsymb[p];
    float nrm = rsqrtf(degc[sp] * degc[dp]);
    int pz0 = pos[p], pz1 = pos[E2P + p];
    prc[i] = (i4){sp, dp, pz0, pz1};
    wn[i] = make_float2(w, nrm);
    const f4* Zs = (const f4*)(Z + (size_t)sp * 16);
    const f4* Zd = (const f4*)(Z + (size_t)dp * 16);
    f4 ls0 = Zs[0], ls1 = Zs[1], ld0 = Zd[0], ld1 = Zd[1];
    float lps[8], lpd[8];
#pragma unroll
    for (int u = 0; u < 4; u++) { lps[u] = ls0[u]; lps[4+u] = ls1[u]; lpd[u] = ld0[u]; lpd[4+u] = ld1[u]; }
    float me[8], mr[8];
    {
        float mx = lps[0], mx2 = lpd[0];
#pragma unroll
        for (int d = 1; d < 8; d++) { mx = fmaxf(mx, lps[d]); mx2 = fmaxf(mx2, lpd[d]); }
        float s = 0.f, s2 = 0.f;
#pragma unroll
        for (int d = 0; d < 8; d++) { me[d] = __expf(lps[d] - mx); s += me[d];
                                      mr[d] = __expf(lpd[d] - mx2); s2 += mr[d]; }
        float rs = 1.f / s, rs2 = 1.f / s2;
#pragma unroll
        for (int d = 0; d < 8; d++) { me[d] *= rs; mr[d] *= rs2; }
    }
    {
        h8 mh, mh2;
#pragma unroll
        for (int d = 0; d < 8; d++) { mh[d] = (_Float16)me[d]; mh2[d] = (_Float16)mr[d]; }
        *(h8*)(M + (size_t)i * 16)     = mh;
        *(h8*)(M + (size_t)i * 16 + 8) = mh2;
    }
    float fe[8], fr[8];
    kprod(RsL, w, me, mr, fe, fr);
    h8 le, lr;
#pragma unroll
    for (int d = 0; d < 8; d++) {
        le[d] = (_Float16)(__logf(fmaxf(fe[d], 1e-12f)) * nrm);
        lr[d] = (_Float16)(__logf(fmaxf(fr[d], 1e-12f)) * nrm);
    }
    *(h8*)(logf + (size_t)pz0 * 8) = le;   // -> dp's segment
    *(h8*)(logf + (size_t)pz1 * 8) = lr;   // -> sp's segment (semi-sequential: sorted by sp)
}

// fused BP step (sorted index i): coalesced state, in-place m update
__global__ __launch_bounds__(256) void k_bpF(const i4* __restrict__ prc,
        const float2* __restrict__ wn, const float* __restrict__ Rs,
        const float* __restrict__ Z, _Float16* __restrict__ M,
        _Float16* __restrict__ logf) {
    __shared__ float RsL[64];
    const int tid = threadIdx.x;
    if (tid < 64) RsL[tid] = Rs[tid];
    __syncthreads();
    int i = blockIdx.x * 256 + tid;
    if (i >= E2P) return;
    i4 c4 = prc[i];
    const int sp = c4[0], dp = c4[1], pz0 = c4[2], pz1 = c4[3];
    float2 wnv = wn[i];
    const float w = wnv.x, nrm = wnv.y;
    const float alpha = Rs[64];
    h8 mhe = *(const h8*)(M + (size_t)i * 16);
    h8 mhr = *(const h8*)(M + (size_t)i * 16 + 8);
    float me[8], mr[8];
#pragma unroll
    for (int d = 0; d < 8; d++) { me[d] = (float)mhe[d]; mr[d] = (float)mhr[d]; }
    float fe[8], fr[8];
    kprod(RsL, w, me, mr, fe, fr);
    float lfe[8], lfr[8];
#pragma unroll
    for (int d = 0; d < 8; d++) {
        lfe[d] = __logf(fmaxf(fe[d], 1e-12f)) * nrm;
        lfr[d] = __logf(fmaxf(fr[d], 1e-12f)) * nrm;
    }
    const f4* Zs = (const f4*)(Z + (size_t)sp * 16);
    const f4* Zd = (const f4*)(Z + (size_t)dp * 16);
    f4 ls0 = Zs[0], ls1 = Zs[1], ss0 = Zs[2], ss1 = Zs[3];
    f4 ld0 = Zd[0], ld1 = Zd[1], sd0 = Zd[2], sd1 = Zd[3];
    float te[8], tr[8];
#pragma unroll
    for (int u = 0; u < 4; u++) {
        te[u]     = ls0[u] + alpha * (ss0[u] - lfr[u]);
        te[4 + u] = ls1[u] + alpha * (ss1[u] - lfr[4 + u]);
        tr[u]     = ld0[u] + alpha * (sd0[u] - lfe[u]);
        tr[4 + u] = ld1[u] + alpha * (sd1[u] - lfe[4 + u]);
    }
    float m1[8], m2[8];
    {
        float mx = te[0], mx2 = tr[0];
#pragma unroll
        for (int d = 1; d < 8; d++) { mx = fmaxf(mx, te[d]); mx2 = fmaxf(mx2, tr[d]); }
        float s = 0.f, s2 = 0.f;
#pragma unroll
        for (int d = 0; d < 8; d++) { m1[d] = __expf(te[d] - mx); s += m1[d];
                                      m2[d] = __expf(tr[d] - mx2); s2 += m2[d]; }
        float rs = 1.f / s, rs2 = 1.f / s2;
        float t1 = 0.f, t2 = 0.f;
#pragma unroll
        for (int d = 0; d < 8; d++) {
            m1[d] = fmaxf(0.8f * me[d] + 0.2f * m1[d] * rs, 1e-12f);  t1 += m1[d];
            m2[d] = fmaxf(0.8f * mr[d] + 0.2f * m2[d] * rs2, 1e-12f); t2 += m2[d];
        }
        float rt1 = 1.f / t1, rt2 = 1.f / t2;
#pragma unroll
        for (int d = 0; d < 8; d++) { m1[d] *= rt1; m2[d] *= rt2; }
    }
    {
        h8 mh, mh2;
#pragma unroll
        for (int d = 0; d < 8; d++) { mh[d] = (_Float16)m1[d]; mh2[d] = (_Float16)m2[d]; }
        *(h8*)(M + (size_t)i * 16)     = mh;
        *(h8*)(M + (size_t)i * 16 + 8) = mh2;
    }
    // new log_f for next iteration's sum
    float fe2[8], fr2[8];
    kprod(RsL, w, m1, m2, fe2, fr2);
    h8 le, lr;
#pragma unroll
    for (int d = 0; d < 8; d++) {
        le[d] = (_Float16)(__logf(fmaxf(fe2[d], 1e-12f)) * nrm);
        lr[d] = (_Float16)(__logf(fmaxf(fr2[d], 1e-12f)) * nrm);
    }
    *(h8*)(logf + (size_t)pz0 * 8) = le;
    *(h8*)(logf + (size_t)pz1 * 8) = lr;
}

// ---------------- sum_in: CSR reduction, h8 loads + 8-lane fold-reduce ----------------
// fin==0: write S to Z[n][8+j].  fin==1: beliefs = softmax(log_phi + alpha*S) -> out.
__global__ void k_sum(const _Float16* __restrict__ logf, const int* __restrict__ base,
                      const int* __restrict__ deg, float* __restrict__ Z,
                      const float* __restrict__ Rs, float* __restrict__ out, int fin) {
    int g = blockIdx.x * 256 + threadIdx.x;
    int n = g >> 3;
    if (n >= NN) return;
    int j = threadIdx.x & 7;
    int b = base[n], cnt = deg[n];
    float acc[8];
#pragma unroll
    for (int d = 0; d < 8; d++) acc[d] = 0.f;
    for (int s = j; s < cnt; s += 8) {
        h8 v = *(const h8*)(logf + (size_t)(b + s) * 8);
#pragma unroll
        for (int d = 0; d < 8; d++) acc[d] += (float)v[d];
    }
    int lane = threadIdx.x & 63;
    float v4[4], v2[2], r;
    {
        bool hi = (lane & 4) != 0;
#pragma unroll
        for (int i = 0; i < 4; i++) {
            float send = hi ? acc[i] : acc[i + 4];
            float recv = __shfl_xor(send, 4, 64);
            v4[i] = (hi ? acc[i + 4] : acc[i]) + recv;
        }
    }
    {
        bool hi = (lane & 2) != 0;
#pragma unroll
        for (int i = 0; i < 2; i++) {
            float send = hi ? v4[i] : v4[i + 2];
            float recv = __shfl_xor(send, 2, 64);
            v2[i] = (hi ? v4[i + 2] : v4[i]) + recv;
        }
    }
    {
        bool hi = (lane & 1) != 0;
        float send = hi ? v2[0] : v2[1];
        float recv = __shfl_xor(send, 1, 64);
        r = (hi ? v2[1] : v2[0]) + recv;
    }
    if (!fin) {
        Z[(size_t)n * 16 + 8 + j] = r;
    } else {
        float alpha = Rs[64];
        float v = Z[(size_t)n * 16 + j] + alpha * r;
        float mx = v;
        mx = fmaxf(mx, __shfl_xor(mx, 1, 64));
        mx = fmaxf(mx, __shfl_xor(mx, 2, 64));
        mx = fmaxf(mx, __shfl_xor(mx, 4, 64));
        float ex = __expf(v - mx);
        float s = ex;
        s += __shfl_xor(s, 1, 64); s += __shfl_xor(s, 2, 64); s += __shfl_xor(s, 4, 64);
        out[(size_t)n * 8 + j] = ex / s;
    }
}

extern "C" void kernel_launch(void* const* d_in, const int* in_sizes, int n_in,
                              void* d_out, int out_size, void* d_ws, size_t ws_size,
                              hipStream_t stream) {
    if (ws_size < WS_NEED) return;
    const float* x        = (const float*)d_in[0];
    const int*   ei       = (const int*)d_in[1];
    const float* enc_w1   = (const float*)d_in[3];
    const float* enc_b1   = (const float*)d_in[4];
    const float* enc_w2   = (const float*)d_in[5];
    const float* enc_b2   = (const float*)d_in[6];
    const float* edge_w1  = (const float*)d_in[7];
    const float* edge_b1  = (const float*)d_in[8];
    const float* edge_w2  = (const float*)d_in[9];
    const float* edge_b2  = (const float*)d_in[10];
    const float* R_raw    = (const float*)d_in[11];
    const float* Rsl      = (const float*)d_in[12];
    const float* mlog     = (const float*)d_in[13];

    char* ws = (char*)d_ws;
    _Float16* hf     = (_Float16*)(ws + OFF_HF16);
    _Float16* logfb  = (_Float16*)(ws + OFF_LOGF);
    float* Zb        = (float*)(ws + OFF_Z);
    int*   deg       = (int*)  (ws + OFF_DEG);
    float* logdeg    = (float*)(ws + OFF_LOGDEG);
    float* degc      = (float*)(ws + OFF_DEGC);
    int*   baseA     = (int*)  (ws + OFF_BASE);
    int*   cnt       = (int*)  (ws + OFF_CNT);
    int*   blk       = (int*)  (ws + OFF_BLK);
    _Float16* Wt     = (_Float16*)(ws + OFF_WT);
    _Float16* Bt     = (_Float16*)(ws + OFF_BT);
    float* Rs        = (float*)(ws + OFF_RS);
    float* wsym      = (float*)(ws + OFF_WSYM);
    int*   pos       = (int*)  (ws + OFF_POS);
    int*   order     = (int*)  (ws + OFF_ORDER);
    int*   base2     = (int*)  (ws + OFF_BASE2);
    int*   ofs2      = (int*)  (ws + OFF_OFS2);
    i4*    prc       = (i4*)   (ws + OFF_PRC);
    float2* wnb      = (float2*)(ws + OFF_WN);
    _Float16* Mb     = (_Float16*)(ws + OFF_M);
    float* outp      = (float*)d_out;

    hipMemsetAsync(deg, 0, (size_t)NN * 4, stream);
    k_deg<<<dim3(EDD / 256), dim3(256), 0, stream>>>(ei, deg);
    k_node<<<dim3(NBLK), dim3(256), 0, stream>>>(deg, logdeg, degc);
    k_prep<<<dim3((256 * 512 + 64 * 544 + 65 + 255) / 256), dim3(256), 0, stream>>>(
        enc_w1, edge_w1, R_raw, Rsl, mlog, Wt, Bt, Rs);
    // CSR build (one-time)
    k_scan1<<<dim3(NBLK), dim3(256), 0, stream>>>(deg, cnt /*incl scratch*/, blk);
    k_scan2<<<dim3(1), dim3(256), 0, stream>>>(blk);
    k_scan3<<<dim3(NBLK), dim3(256), 0, stream>>>(cnt, deg, blk, baseA);
    hipMemsetAsync(cnt, 0, (size_t)NN * 4, stream);
    k_pos<<<dim3(EDD / 256), dim3(256), 0, stream>>>(ei, baseA, cnt, pos);
    // pair counting-sort by src (one-time)
    hipMemsetAsync(ofs2, 0, (size_t)NN * 4, stream);
    k_cnt2<<<dim3(EBLK), dim3(256), 0, stream>>>(ei, ofs2);
    k_scan1<<<dim3(NBLK), dim3(256), 0, stream>>>(ofs2, cnt, blk);
    k_scan2<<<dim3(1), dim3(256), 0, stream>>>(blk);
    k_scan3<<<dim3(NBLK), dim3(256), 0, stream>>>(cnt, ofs2, blk, base2);
    hipMemsetAsync(ofs2, 0, (size_t)NN * 4, stream);
    k_order<<<dim3(EBLK), dim3(256), 0, stream>>>(ei, base2, ofs2, order);
    // encoder + edge MLP
    k_enc<<<dim3((NN + 63) / 64), dim3(256), 0, stream>>>(x, Wt, enc_b1, hf);
    k_logits<<<dim3(NBLK), dim3(256), 0, stream>>>(hf, enc_w2, enc_b2, Zb);
    k_edge<<<dim3(E2P / 128), dim3(256), 0, stream>>>(ei, hf, logdeg, Bt, edge_b1,
                                                      edge_w2, edge_b2, wsym);
    // BP loop (logfb aliases hf — hf is dead from here on)
    k_init<<<dim3(EBLK), dim3(256), 0, stream>>>(ei, wsym, degc, Rs, Zb, pos, order,
                                                 prc, wnb, Mb, logfb);
    k_sum<<<dim3((NN * 8 + 255) / 256), dim3(256), 0, stream>>>(logfb, baseA, deg, Zb,
                                                                Rs, outp, 0);
    for (int t = 0; t < 10; t++) {
        k_bpF<<<dim3(EBLK), dim3(256), 0, stream>>>(prc, wnb, Rs, Zb, Mb, logfb);
        k_sum<<<dim3((NN * 8 + 255) / 256), dim3(256), 0, stream>>>(logfb, baseA, deg, Zb,
                                                                    Rs, outp, (t == 9) ? 1 : 0);
    }
    (void)in_sizes; (void)n_in; (void)out_size;
}